// Round 4
// baseline (209.275 us; speedup 1.0000x reference)
//
#include <hip/hip_runtime.h>

// SparsemaxBisectLoss: x (8192 x 32000 f32), target (8192 int32) -> scalar f32
//
// tau in [max-1, max-1/d] => only elements > max-1 matter (~100 of 32000 for
// N(0,1)). Stream each row ONCE (memory-bound: 1.048 GB mandatory read):
// per-wave sample threshold thr = wave_chunk0_max - 1 (<= row_max - 1, so the
// candidate set is a superset of the support); push candidates to LDS; solve
// tau exactly with Michelot active-set iteration (the limit of the reference's
// 50-step bisection; threshold is 8.6e-2, we agree to ~1 ulp).
//
// Round-4 change: FUSED finalization — each block atomicAdds loss/n into
// out[0] (zeroed via hipMemsetAsync each launch). Removes the mean kernel,
// its launch gap, and the row_loss round-trip. 8192 single-address f32
// atomics spread over ~170 us (~48/us) — no contention stall.

#define ROW_LEN 32000
#define ROW_V4  8000      // float4 per row
#define CAP     4096      // candidate capacity (expected ~100/row)

typedef float v4f __attribute__((ext_vector_type(4)));

__device__ __forceinline__ float max4(v4f v) {
    return fmaxf(fmaxf(v[0], v[1]), fmaxf(v[2], v[3]));
}

__global__ __launch_bounds__(256) void sparsemax_row_kernel(
    const float* __restrict__ x, const int* __restrict__ target,
    float* __restrict__ out, float inv_n, int n_rows)
{
    __shared__ float s_cand[CAP];
    __shared__ int   s_cnt;

    const int row  = blockIdx.x;
    if (row >= n_rows) return;
    const int t    = threadIdx.x;
    const int lane = t & 63;
    const int wid  = t >> 6;

    const float* rowp = x + (size_t)row * ROW_LEN;
    const v4f*   rowv = (const v4f*)rowp;

    float x_tgt = 0.f;
    if (t == 0) {
        s_cnt = 0;
        x_tgt = rowp[target[row]];   // single gather, latency hidden
    }

    // ---- chunk 0: 8 x float4 per thread (2048 v4 = 8192 floats, all in-range)
    v4f v[8];
    #pragma unroll
    for (int k = 0; k < 8; ++k)
        v[k] = __builtin_nontemporal_load(rowv + t + k * 256);

    // per-wave threshold from this wave's 2048-element sample (<= row_max - 1)
    float lm = -1e30f;
    #pragma unroll
    for (int k = 0; k < 8; ++k) lm = fmaxf(lm, max4(v[k]));
    #pragma unroll
    for (int o = 32; o >= 1; o >>= 1) lm = fmaxf(lm, __shfl_xor(lm, o));
    const float thr = lm - 1.0f;

    __syncthreads();   // s_cnt = 0 visible before any push

    // ---- filter chunk 0, then stream+filter chunks 1..3
    for (int c = 0; ; ++c) {
        #pragma unroll
        for (int k = 0; k < 8; ++k) {
            if (max4(v[k]) > thr) {
                #pragma unroll
                for (int e = 0; e < 4; ++e) {
                    const float val = v[k][e];
                    if (val > thr) {
                        const int idx = atomicAdd(&s_cnt, 1);
                        if (idx < CAP) s_cand[idx] = val;
                    }
                }
            }
        }
        if (c == 3) break;
        const int base = (c + 1) * 2048 + t;
        #pragma unroll
        for (int k = 0; k < 8; ++k) {
            const int idx = base + k * 256;
            if (idx < ROW_V4) v[k] = __builtin_nontemporal_load(rowv + idx);
            else              v[k] = (v4f){-1e30f, -1e30f, -1e30f, -1e30f};
        }
    }
    __syncthreads();

    // ---- epilogue on wave 0: exact tau via Michelot, then loss
    if (wid == 0) {
        int m = s_cnt;
        if (m > CAP) m = CAP;

        float tau = -1e30f;   // first pass includes all candidates
        int c_prev = -1;
        for (int it = 0; it < 100; ++it) {
            float s = 0.f; int cnt = 0;
            for (int j = lane; j < m; j += 64) {
                const float cv = s_cand[j];
                if (cv > tau) { s += cv; cnt++; }
            }
            #pragma unroll
            for (int o = 32; o >= 1; o >>= 1) {
                s   += __shfl_xor(s, o);
                cnt += __shfl_xor(cnt, o);
            }
            const float tau_new = (s - 1.0f) / (float)cnt;
            if (cnt == c_prev) { tau = tau_new; break; }  // active set stable
            c_prev = cnt;
            tau = tau_new;
        }

        float sp = 0.f, sp2 = 0.f, spx = 0.f;
        for (int j = lane; j < m; j += 64) {
            const float cv = s_cand[j];
            const float p = cv - tau;
            if (p > 0.f) { sp += p; sp2 += p * p; spx += p * cv; }
        }
        #pragma unroll
        for (int o = 32; o >= 1; o >>= 1) {
            sp  += __shfl_xor(sp, o);
            sp2 += __shfl_xor(sp2, o);
            spx += __shfl_xor(spx, o);
        }
        if (lane == 0) {
            const float inv  = 1.0f / sp;                 // ensure_sum_one
            const float loss = 0.5f * (1.0f - sp2 * inv * inv)
                             + spx * inv - x_tgt;
            atomicAdd(out, loss * inv_n);                 // fused mean
        }
    }
}

extern "C" void kernel_launch(void* const* d_in, const int* in_sizes, int n_in,
                              void* d_out, int out_size, void* d_ws, size_t ws_size,
                              hipStream_t stream)
{
    const float* x      = (const float*)d_in[0];
    const int*   target = (const int*)d_in[1];
    float*       out    = (float*)d_out;
    const int n_rows = in_sizes[1];          // 8192

    hipMemsetAsync(d_out, 0, sizeof(float), stream);   // accumulator init (capturable)
    sparsemax_row_kernel<<<n_rows, 256, 0, stream>>>(x, target, out,
                                                     1.0f / (float)n_rows, n_rows);
}

// Round 5
// 177.151 us; speedup vs baseline: 1.1813x; 1.1813x over previous
//
#include <hip/hip_runtime.h>

// SparsemaxBisectLoss: x (8192 x 32000 f32), target (8192 int32) -> scalar f32
//
// tau in [max-1, max-1/d] => only elements > max-1 matter (~100 of 32000 for
// N(0,1)). Stream each row ONCE (memory-bound: 1.048 GB mandatory read):
// per-wave sample threshold thr = wave_chunk0_max - 1 (<= row_max - 1, so the
// candidate set is a superset of the support); push candidates to LDS; solve
// tau exactly with Michelot active-set iteration (the limit of the reference's
// 50-step bisection; threshold is 8.6e-2, we agree to ~1 ulp).
//
// Round-5: REVERT to round-3 structure. Round-4's fused single-address
// device-scope atomicAdd regressed +32us (8192 serialized cross-XCD RMWs
// ~= 4ns each ~= 33us — matches). Two-kernel version: row kernel at
// ~6.09 TB/s (97% of measured streaming ceiling) + 3us deterministic reduce.

#define ROW_LEN 32000
#define ROW_V4  8000      // float4 per row
#define CAP     4096      // candidate capacity (expected ~100/row)

typedef float v4f __attribute__((ext_vector_type(4)));

__device__ __forceinline__ float max4(v4f v) {
    return fmaxf(fmaxf(v[0], v[1]), fmaxf(v[2], v[3]));
}

__global__ __launch_bounds__(256) void sparsemax_row_kernel(
    const float* __restrict__ x, const int* __restrict__ target,
    float* __restrict__ row_loss, int n_rows)
{
    __shared__ float s_cand[CAP];
    __shared__ int   s_cnt;

    const int row  = blockIdx.x;
    if (row >= n_rows) return;
    const int t    = threadIdx.x;
    const int lane = t & 63;
    const int wid  = t >> 6;

    const float* rowp = x + (size_t)row * ROW_LEN;
    const v4f*   rowv = (const v4f*)rowp;

    float x_tgt = 0.f;
    if (t == 0) {
        s_cnt = 0;
        x_tgt = rowp[target[row]];   // single gather, latency hidden
    }

    // ---- chunk 0: 8 x float4 per thread (2048 v4 = 8192 floats, all in-range)
    v4f v[8];
    #pragma unroll
    for (int k = 0; k < 8; ++k)
        v[k] = __builtin_nontemporal_load(rowv + t + k * 256);

    // per-wave threshold from this wave's 2048-element sample (<= row_max - 1)
    float lm = -1e30f;
    #pragma unroll
    for (int k = 0; k < 8; ++k) lm = fmaxf(lm, max4(v[k]));
    #pragma unroll
    for (int o = 32; o >= 1; o >>= 1) lm = fmaxf(lm, __shfl_xor(lm, o));
    const float thr = lm - 1.0f;

    __syncthreads();   // s_cnt = 0 visible before any push

    // ---- filter chunk 0, then stream+filter chunks 1..3
    for (int c = 0; ; ++c) {
        #pragma unroll
        for (int k = 0; k < 8; ++k) {
            if (max4(v[k]) > thr) {
                #pragma unroll
                for (int e = 0; e < 4; ++e) {
                    const float val = v[k][e];
                    if (val > thr) {
                        const int idx = atomicAdd(&s_cnt, 1);
                        if (idx < CAP) s_cand[idx] = val;
                    }
                }
            }
        }
        if (c == 3) break;
        const int base = (c + 1) * 2048 + t;
        #pragma unroll
        for (int k = 0; k < 8; ++k) {
            const int idx = base + k * 256;
            if (idx < ROW_V4) v[k] = __builtin_nontemporal_load(rowv + idx);
            else              v[k] = (v4f){-1e30f, -1e30f, -1e30f, -1e30f};
        }
    }
    __syncthreads();

    // ---- epilogue on wave 0: exact tau via Michelot, then loss
    if (wid == 0) {
        int m = s_cnt;
        if (m > CAP) m = CAP;

        float tau = -1e30f;   // first pass includes all candidates
        int c_prev = -1;
        for (int it = 0; it < 100; ++it) {
            float s = 0.f; int cnt = 0;
            for (int j = lane; j < m; j += 64) {
                const float cv = s_cand[j];
                if (cv > tau) { s += cv; cnt++; }
            }
            #pragma unroll
            for (int o = 32; o >= 1; o >>= 1) {
                s   += __shfl_xor(s, o);
                cnt += __shfl_xor(cnt, o);
            }
            const float tau_new = (s - 1.0f) / (float)cnt;
            if (cnt == c_prev) { tau = tau_new; break; }  // active set stable
            c_prev = cnt;
            tau = tau_new;
        }

        float sp = 0.f, sp2 = 0.f, spx = 0.f;
        for (int j = lane; j < m; j += 64) {
            const float cv = s_cand[j];
            const float p = cv - tau;
            if (p > 0.f) { sp += p; sp2 += p * p; spx += p * cv; }
        }
        #pragma unroll
        for (int o = 32; o >= 1; o >>= 1) {
            sp  += __shfl_xor(sp, o);
            sp2 += __shfl_xor(sp2, o);
            spx += __shfl_xor(spx, o);
        }
        if (lane == 0) {
            const float inv  = 1.0f / sp;                 // ensure_sum_one
            const float loss = 0.5f * (1.0f - sp2 * inv * inv)
                             + spx * inv - x_tgt;
            row_loss[row] = loss;
        }
    }
}

// Deterministic mean reduction of n row losses -> out[0]
__global__ __launch_bounds__(256) void mean_kernel(
    const float* __restrict__ row_loss, float* __restrict__ out, int n)
{
    __shared__ float s_red[4];
    const int t = threadIdx.x;
    const int lane = t & 63, wid = t >> 6;
    float s = 0.f;
    for (int i = t; i < n; i += 256) s += row_loss[i];
    #pragma unroll
    for (int o = 32; o >= 1; o >>= 1) s += __shfl_xor(s, o);
    if (lane == 0) s_red[wid] = s;
    __syncthreads();
    if (t == 0)
        out[0] = (s_red[0] + s_red[1] + s_red[2] + s_red[3]) / (float)n;
}

extern "C" void kernel_launch(void* const* d_in, const int* in_sizes, int n_in,
                              void* d_out, int out_size, void* d_ws, size_t ws_size,
                              hipStream_t stream)
{
    const float* x      = (const float*)d_in[0];
    const int*   target = (const int*)d_in[1];
    float*       out    = (float*)d_out;
    const int n_rows = in_sizes[1];          // 8192
    float* row_loss = (float*)d_ws;

    sparsemax_row_kernel<<<n_rows, 256, 0, stream>>>(x, target, row_loss, n_rows);
    mean_kernel<<<1, 256, 0, stream>>>(row_loss, out, n_rows);
}